// Round 2
// baseline (898.908 us; speedup 1.0000x reference)
//
#include <hip/hip_runtime.h>

#define NB   4
#define CIN  64
#define COUT 64
#define HH   160
#define WW   160
#define HW   (HH * WW)

// ---------------------------------------------------------------------------
// Pre-pass: transpose weight [O][C][3][3] -> wt[t][c][o]  (t = ky*3+kx)
// so the main kernel reads 64 consecutive o's at a wave-uniform address
// (compiler scalarizes -> s_load, inner loop becomes v_fmac v, s, v).
// ---------------------------------------------------------------------------
__global__ void wt_transpose_kernel(const float* __restrict__ w,
                                    float* __restrict__ wt) {
    int i = blockIdx.x * 256 + threadIdx.x;       // i = (t*64 + c)*64 + o
    if (i < 9 * CIN * COUT) {
        int o = i & 63;
        int c = (i >> 6) & 63;
        int t = i >> 12;
        wt[i] = w[(o * CIN + c) * 9 + t];
    }
}

// ---------------------------------------------------------------------------
// Main kernel: 256 threads (4 waves) per 64 consecutive output pixels.
// lane = pixel. Wave w accumulates channels [16w, 16w+16) into 64 fp32
// accumulators per lane; cross-wave reduction through LDS (2 chunks of 32
// outputs, padded rows -> conflict-free).
// Geometry (4 corner indices + 4 bilinear coefs per tap) precomputed into
// registers; c-outer / t-inner ordering keeps each channel's ~2.6 KB gather
// region L1-hot for all 36 gathers.
// ---------------------------------------------------------------------------
__global__ __launch_bounds__(256) void pdconv_kernel(
    const float* __restrict__ in,        // [B][CIN][H][W]
    const float* __restrict__ wt,        // [9][CIN][COUT]
    const float* __restrict__ rate_map,  // [B][1][H][W]
    const float* __restrict__ bias,      // [COUT]
    float* __restrict__ out)             // [B][COUT][H][W]
{
    const int tid  = threadIdx.x;
    const int lane = tid & 63;
    const int wave = tid >> 6;

    // XCD-bijective swizzle: 1600 blocks, 1600 % 8 == 0.
    const int nblk = gridDim.x;             // 1600
    const int cpx  = nblk >> 3;             // 200 blocks per XCD
    const int bid  = (blockIdx.x & 7) * cpx + (blockIdx.x >> 3);

    const int p    = bid * 64 + lane;       // flat pixel over (b,y,x)
    const int b    = p / HW;                // 25600 % 64 == 0
    const int pix  = p - b * HW;
    const int y    = pix / WW;
    const int x    = pix - y * WW;

    const float rate = rate_map[p];
    const float fy = (float)y, fx = (float)x;

    // ---- per-tap geometry into registers: 36 coefs + 36 indices ----
    float cf[9][4];
    int   ix[9][4];
#pragma unroll
    for (int t = 0; t < 9; ++t) {
        const int ky = t / 3;
        const int kx = t - 3 * ky;
        const float sy  = fy + (float)(ky - 1) * rate;
        const float sx  = fx + (float)(kx - 1) * rate;
        const float y0f = floorf(sy), x0f = floorf(sx);
        const float wy  = sy - y0f,   wx  = sx - x0f;
        const int   y0  = (int)y0f,   x0  = (int)x0f;
        const int   y1  = y0 + 1,     x1  = x0 + 1;

        const float omwy = 1.0f - wy, omwx = 1.0f - wx;
        const float vy0 = (y0 >= 0 && y0 < HH) ? 1.0f : 0.0f;
        const float vy1 = (y1 >= 0 && y1 < HH) ? 1.0f : 0.0f;
        const float vx0 = (x0 >= 0 && x0 < WW) ? 1.0f : 0.0f;
        const float vx1 = (x1 >= 0 && x1 < WW) ? 1.0f : 0.0f;

        cf[t][0] = omwy * omwx * vy0 * vx0;
        cf[t][1] = omwy * wx   * vy0 * vx1;
        cf[t][2] = wy   * omwx * vy1 * vx0;
        cf[t][3] = wy   * wx   * vy1 * vx1;

        const int cy0 = min(max(y0, 0), HH - 1);
        const int cy1 = min(max(y1, 0), HH - 1);
        const int cx0 = min(max(x0, 0), WW - 1);
        const int cx1 = min(max(x1, 0), WW - 1);
        ix[t][0] = cy0 * WW + cx0;
        ix[t][1] = cy0 * WW + cx1;
        ix[t][2] = cy1 * WW + cx0;
        ix[t][3] = cy1 * WW + cx1;
    }

    float acc[COUT];
#pragma unroll
    for (int o = 0; o < COUT; ++o) acc[o] = 0.0f;

    const int c0 = wave * 16;                               // this wave's channels
    const float* img = in + ((size_t)b * CIN + c0) * HW;

#pragma unroll 1
    for (int cc = 0; cc < 16; ++cc) {
        const float* ch = img + (size_t)cc * HW;
        const float* wr0 = wt + (c0 + cc) * COUT;           // + t*CIN*COUT per tap
#pragma unroll
        for (int t = 0; t < 9; ++t) {
            const float a = cf[t][0] * ch[ix[t][0]]
                          + cf[t][1] * ch[ix[t][1]]
                          + cf[t][2] * ch[ix[t][2]]
                          + cf[t][3] * ch[ix[t][3]];
            const float* wr = wr0 + t * (CIN * COUT);       // wave-uniform -> s_load
#pragma unroll
            for (int o = 0; o < COUT; ++o)
                acc[o] = fmaf(wr[o], a, acc[o]);
        }
    }

    // ---- cross-wave reduction via LDS, 2 chunks of 32 outputs ----
    __shared__ float red[4][64][33];                        // 33: pad -> conflict-free
    float* op = out + (size_t)b * COUT * HW + pix;

#pragma unroll 1
    for (int chunk = 0; chunk < 2; ++chunk) {
#pragma unroll
        for (int j = 0; j < 32; ++j)
            red[wave][lane][j] = acc[chunk * 32 + j];
        __syncthreads();
#pragma unroll
        for (int jj = 0; jj < 8; ++jj) {
            const int ol = wave * 8 + jj;
            const float s = red[0][lane][ol] + red[1][lane][ol]
                          + red[2][lane][ol] + red[3][lane][ol];
            const int o = chunk * 32 + ol;
            op[(size_t)o * HW] = s + bias[o];
        }
        __syncthreads();
    }
}

extern "C" void kernel_launch(void* const* d_in, const int* in_sizes, int n_in,
                              void* d_out, int out_size, void* d_ws, size_t ws_size,
                              hipStream_t stream) {
    (void)in_sizes; (void)n_in; (void)out_size; (void)ws_size;
    const float* in   = (const float*)d_in[0];
    const float* w    = (const float*)d_in[1];
    const float* rm   = (const float*)d_in[2];
    const float* bias = (const float*)d_in[3];
    float* out = (float*)d_out;
    float* wtb = (float*)d_ws;   // 147,456 B scratch for transposed weight

    hipLaunchKernelGGL(wt_transpose_kernel, dim3(144), dim3(256), 0, stream, w, wtb);

    const int nblocks = (NB * HW) / 64;  // 1600
    hipLaunchKernelGGL(pdconv_kernel, dim3(nblocks), dim3(256), 0, stream,
                       in, wtb, rm, bias, out);
}